// Round 4
// baseline (3538.064 us; speedup 1.0000x reference)
//
#include <hip/hip_runtime.h>
#include <math.h>

#define DMODEL 2048
#define NHEADS 16
#define DK     128
#define BATCH  4
#define SEQ    2048
#define MROWS  (BATCH*SEQ)   // 8192

typedef unsigned short u16;
typedef short s16x8 __attribute__((ext_vector_type(8)));
typedef u16   u16x4 __attribute__((ext_vector_type(4)));
typedef u16   u16x8 __attribute__((ext_vector_type(8)));
typedef float f32x4 __attribute__((ext_vector_type(4)));
typedef unsigned int u32x4 __attribute__((ext_vector_type(4)));

#define MFMA16(a, b, c) __builtin_amdgcn_mfma_f32_16x16x32_bf16((a), (b), (c), 0, 0, 0)

__device__ __forceinline__ u16 f2bf(float f) {       // RNE fp32 -> bf16 bits
    unsigned u = __builtin_bit_cast(unsigned, f);
    unsigned r = (u + 0x7fffu + ((u >> 16) & 1u)) >> 16;
    return (u16)r;
}
// truncating fp32 -> bf16 (1 op). Use ONLY where a lo-residual is also kept:
// hi = trunc(x), lo = trunc(x - hi) captures 16+ mantissa bits exactly.
__device__ __forceinline__ u16 f2bf_t(float f) {
    return (u16)(__builtin_bit_cast(unsigned, f) >> 16);
}
__device__ __forceinline__ float bf2f(u16 h) {
    unsigned u = ((unsigned)h) << 16;
    return __builtin_bit_cast(float, u);
}

// async global->LDS, 16B per lane. LDS dest must be linear in lane order.
__device__ __forceinline__ void gld_lds16(const u16* g, u16* l) {
    __builtin_amdgcn_global_load_lds(
        (const __attribute__((address_space(1))) unsigned int*)g,
        (__attribute__((address_space(3))) unsigned int*)l,
        16, 0, 0);
}

// ---------------------------------------------------------------------------
// fp32 -> (bf16 hi, bf16 lo) split, elementwise.
// ---------------------------------------------------------------------------
__global__ __launch_bounds__(256)
void split_bf16_kernel(const float* __restrict__ src,
                       u16* __restrict__ hi, u16* __restrict__ lo, int n8) {
    const int stride = gridDim.x * blockDim.x;
    for (int i = blockIdx.x * blockDim.x + threadIdx.x; i < n8; i += stride) {
        const float4 f0 = ((const float4*)src)[2 * i];
        const float4 f1 = ((const float4*)src)[2 * i + 1];
        const float f[8] = {f0.x, f0.y, f0.z, f0.w, f1.x, f1.y, f1.z, f1.w};
        u16x8 h8, l8;
#pragma unroll
        for (int j = 0; j < 8; ++j) {
            const u16 hb = f2bf_t(f[j]);
            h8[j] = hb;
            l8[j] = f2bf_t(f[j] - bf2f(hb));
        }
        ((u16x8*)hi)[i] = h8;
        ((u16x8*)lo)[i] = l8;
    }
}

// ---------------------------------------------------------------------------
// Split-bf16 MFMA NT-GEMM core: C[m,n] = sum_k A[m,k]*B[n,k] (~fp32 accuracy)
// via Ah*Bh + Al*Bh + Ah*Bl. 128x128 tile, BK=32, 4 waves (each 64x64).
// ---------------------------------------------------------------------------
__device__ __forceinline__ void gemm128_split_core(
        const u16* __restrict__ Ahg, const u16* __restrict__ Alg,
        const u16* __restrict__ Bhg, const u16* __restrict__ Blg,
        const int bm, const int bn, f32x4 (&acc)[4][4]) {
    __shared__ __align__(16) u16 Ah[128 * 32];
    __shared__ __align__(16) u16 Al[128 * 32];
    __shared__ __align__(16) u16 Bh[128 * 32];
    __shared__ __align__(16) u16 Bl[128 * 32];

    const int t    = threadIdx.x;
    const int lane = t & 63;
    const int wave = t >> 6;

    const int srow = t >> 2;            // 0..63
    const int skof = (t & 3) * 8;       // k elem offset 0,8,16,24
    const size_t ga0 = (size_t)(bm + srow) * DMODEL + skof;
    const size_t ga1 = (size_t)(bm + srow + 64) * DMODEL + skof;
    const size_t gb0 = (size_t)(bn + srow) * DMODEL + skof;
    const size_t gb1 = (size_t)(bn + srow + 64) * DMODEL + skof;
    const int l0 = srow * 32 + skof;
    const int l1 = l0 + 64 * 32;

    const int lm = lane & 15;
    const int lg = lane >> 4;
    const int wr = (wave >> 1) * 64;
    const int wc = (wave & 1) * 64;
    const int aoff = (wr + lm) * 32 + lg * 8;
    const int boff = (wc + lm) * 32 + lg * 8;

    for (int kt = 0; kt < DMODEL; kt += 32) {
        __syncthreads();
        gld_lds16(Ahg + ga0 + kt, &Ah[l0]);
        gld_lds16(Ahg + ga1 + kt, &Ah[l1]);
        gld_lds16(Alg + ga0 + kt, &Al[l0]);
        gld_lds16(Alg + ga1 + kt, &Al[l1]);
        gld_lds16(Bhg + gb0 + kt, &Bh[l0]);
        gld_lds16(Bhg + gb1 + kt, &Bh[l1]);
        gld_lds16(Blg + gb0 + kt, &Bl[l0]);
        gld_lds16(Blg + gb1 + kt, &Bl[l1]);
        __syncthreads();

        s16x8 af[4], alf[4];
#pragma unroll
        for (int i = 0; i < 4; ++i) {
            af[i]  = *(const s16x8*)&Ah[aoff + i * 16 * 32];
            alf[i] = *(const s16x8*)&Al[aoff + i * 16 * 32];
        }
#pragma unroll
        for (int j = 0; j < 4; ++j) {
            const s16x8 bf  = *(const s16x8*)&Bh[boff + j * 16 * 32];
            const s16x8 blf = *(const s16x8*)&Bl[boff + j * 16 * 32];
#pragma unroll
            for (int i = 0; i < 4; ++i) {
                acc[i][j] = MFMA16(af[i],  bf,  acc[i][j]);
                acc[i][j] = MFMA16(alf[i], bf,  acc[i][j]);
                acc[i][j] = MFMA16(af[i],  blf, acc[i][j]);
            }
        }
    }
}

// QKV projection (MFMA). Q,K -> bf16 hi/lo [BH,S,128] (Q pre-scaled by
// 1/sqrt(dk)). V -> bf16 TRANSPOSED [BH,128,S].
__global__ __launch_bounds__(256)
void qkv_proj_mfma(const u16* __restrict__ Xhi, const u16* __restrict__ Xlo,
                   const u16* __restrict__ Wh,  const u16* __restrict__ Wl,
                   u16* __restrict__ Qhi, u16* __restrict__ Qlo,
                   u16* __restrict__ Khi, u16* __restrict__ Klo,
                   u16* __restrict__ Vt) {
    const int g  = blockIdx.x >> 4;          // 0=Q 1=K 2=V
    const int nb = blockIdx.x & 15;          // head
    const int bm = blockIdx.y * 128;
    const size_t WE = (size_t)DMODEL * DMODEL;

    f32x4 acc[4][4] = {};
    gemm128_split_core(Xhi, Xlo, Wh + g * WE, Wl + g * WE, bm, nb * 128, acc);

    const int lane = threadIdx.x & 63;
    const int wave = threadIdx.x >> 6;
    const int lm = lane & 15;
    const int lg = lane >> 4;
    const int wr = (wave >> 1) * 64;
    const int wc = (wave & 1) * 64;

    if (g < 2) {
        u16* hiP = (g == 0) ? Qhi : Khi;
        u16* loP = (g == 0) ? Qlo : Klo;
        const float sc = (g == 0) ? 0.08838834764831845f : 1.0f;
#pragma unroll
        for (int i = 0; i < 4; ++i) {
#pragma unroll
            for (int r = 0; r < 4; ++r) {
                const int s  = bm + wr + i * 16 + lg * 4 + r;
                const int bb = s >> 11;
                const size_t base =
                    ((size_t)(bb * NHEADS + nb) * SEQ + (s & 2047)) * DK + wc + lm;
#pragma unroll
                for (int j = 0; j < 4; ++j) {
                    const float y = acc[i][j][r] * sc;
                    const u16 hb = f2bf_t(y);
                    hiP[base + j * 16] = hb;
                    loP[base + j * 16] = f2bf_t(y - bf2f(hb));
                }
            }
        }
    } else {
        // V transposed: Vt[bh][d][s]. Single bf16 -> keep RNE (dominant
        // error term of the whole pipeline).
#pragma unroll
        for (int i = 0; i < 4; ++i) {
            const int s0 = bm + wr + i * 16 + lg * 4;
            const int bb = s0 >> 11;
            const int ss = s0 & 2047;
            const size_t rowb = (size_t)(bb * NHEADS + nb) * DK;
#pragma unroll
            for (int j = 0; j < 4; ++j) {
                u16x4 v;
#pragma unroll
                for (int r = 0; r < 4; ++r) v[r] = f2bf(acc[i][j][r]);
                *(u16x4*)(Vt + (rowb + wc + j * 16 + lm) * SEQ + ss) = v;
            }
        }
    }
}

// out = O @ wo^T (MFMA split), fp32 output.
__global__ __launch_bounds__(256)
void out_proj_mfma(const u16* __restrict__ Ohi, const u16* __restrict__ Olo,
                   const u16* __restrict__ Woh, const u16* __restrict__ Wol,
                   float* __restrict__ out) {
    const int bn = blockIdx.x * 128;
    const int bm = blockIdx.y * 128;
    f32x4 acc[4][4] = {};
    gemm128_split_core(Ohi, Olo, Woh, Wol, bm, bn, acc);

    const int lane = threadIdx.x & 63;
    const int wave = threadIdx.x >> 6;
    const int lm = lane & 15;
    const int lg = lane >> 4;
    const int wr = (wave >> 1) * 64;
    const int wc = (wave & 1) * 64;
#pragma unroll
    for (int i = 0; i < 4; ++i) {
#pragma unroll
        for (int r = 0; r < 4; ++r) {
            const int row = bm + wr + i * 16 + lg * 4 + r;
            float* dst = out + (size_t)row * DMODEL + bn + wc + lm;
#pragma unroll
            for (int j = 0; j < 4; ++j) dst[j * 16] = acc[i][j][r];
        }
    }
}

// ---------------------------------------------------------------------------
// MFMA flash attention, split-bf16.
// This round: (1) K/V LDS OVERLAY -- K(hi+lo) live only in the S phase, V only
// in PV, so they share one 17.4KB buffer; total LDS 26624B -> 6 blocks/CU
// (was 36864B -> 4). Costs 4 barriers/tile instead of 2, paid for by +50%
// block-level TLP (kernel is latency-bound: all pipes <45%).
// (2) T13 defer-max (THR=8): skip the O-rescale (4 exp + 36 mul) unless the
// tile max exceeds the running max by >8; P bounded by e^8, exact math.
// ---------------------------------------------------------------------------
__global__ __launch_bounds__(256, 6)
void attn_kernel(const u16* __restrict__ Qhi, const u16* __restrict__ Qlo,
                 const u16* __restrict__ KhiG, const u16* __restrict__ KloG,
                 const u16* __restrict__ VtG,
                 u16* __restrict__ Ohi, u16* __restrict__ Olo) {
    // K-phase: Khs = KV[0..4351] ([32][136]), Kls = KV[4352..8703]
    // V-phase: Vs overlays KV[0..5119] ([128][40])
    __shared__ __align__(16) u16 KV[2 * 32 * 136];
    __shared__ unsigned int Pb[64][36];  // packed (phi | plo<<16)
#define KHS(r, c) KV[(r) * 136 + (c)]
#define KLS(r, c) KV[4352 + (r) * 136 + (c)]
#define VSS(d, k) KV[(d) * 40 + (k)]

    // XCD-bijective swizzle: 2048 blocks, 8 XCDs, 256 per XCD.
    const int idlin = blockIdx.y * gridDim.x + blockIdx.x;   // 0..2047
    const int swz   = (idlin & 7) * 256 + (idlin >> 3);
    const int bh    = swz >> 5;
    const int q0    = (swz & 31) * 64;

    const int t  = threadIdx.x;
    const int l  = t & 63;
    const int w  = t >> 6;
    const int lm = l & 15;       // "m/n" lane index
    const int lg = l >> 4;       // k-quad
    const int woff = w * 16;

    // ---- load Q fragments (A-layout: m=lm, k=kb*32+lg*8+j) ----
    s16x8 qh[4], ql[4];
    {
        const size_t qrow = (size_t)bh * SEQ + q0 + woff + lm;
#pragma unroll
        for (int kb = 0; kb < 4; ++kb) {
            const size_t off = qrow * DK + kb * 32 + lg * 8;
            qh[kb] = *(const s16x8*)(Qhi + off);
            ql[kb] = *(const s16x8*)(Qlo + off);
        }
    }

    f32x4 o[8];
#pragma unroll
    for (int nt = 0; nt < 8; ++nt) o[nt] = (f32x4){0.f, 0.f, 0.f, 0.f};
    float m[4] = {-1e30f, -1e30f, -1e30f, -1e30f};
    float lsm[4] = {0.f, 0.f, 0.f, 0.f};

    // staging indices
    const int skey = t >> 3;            // 0..31
    const int sdb  = (t & 7) * 16;      // dim base for K staging
    const int vdim = t >> 1;            // 0..127
    const int vkb  = (t & 1) * 16;      // key base for V staging
    const u16* Kh_base = KhiG + ((size_t)bh * SEQ + skey) * DK + sdb;
    const u16* Kl_base = KloG + ((size_t)bh * SEQ + skey) * DK + sdb;
    const u16* Vt_base = VtG + ((size_t)bh * DK + vdim) * SEQ + vkb;

    // ---- T14 prologue: prefetch tile 0 into registers ----
    u16x8 pk0 = *(const u16x8*)(Kh_base);
    u16x8 pk1 = *(const u16x8*)(Kh_base + 8);
    u16x8 pl0 = *(const u16x8*)(Kl_base);
    u16x8 pl1 = *(const u16x8*)(Kl_base + 8);
    u16x8 pv0 = *(const u16x8*)(Vt_base);
    u16x8 pv1 = *(const u16x8*)(Vt_base + 8);

    for (int kt = 0; kt < SEQ; kt += 32) {
        // issue next tile's loads NOW; latency spans barriers + compute.
        const int ktn = (kt + 32 < SEQ) ? kt + 32 : 0;
        const u16* khn = Kh_base + (size_t)ktn * DK;
        const u16* kln = Kl_base + (size_t)ktn * DK;
        const u16* vpn = Vt_base + ktn;
        const u16x8 nk0 = *(const u16x8*)khn;
        const u16x8 nk1 = *(const u16x8*)(khn + 8);
        const u16x8 nl0 = *(const u16x8*)kln;
        const u16x8 nl1 = *(const u16x8*)(kln + 8);
        const u16x8 nv0 = *(const u16x8*)vpn;
        const u16x8 nv1 = *(const u16x8*)(vpn + 8);

        __syncthreads();                 // A: prev PV done -> KV writable
        *(u16x8*)&KHS(skey, sdb)     = pk0;
        *(u16x8*)&KHS(skey, sdb + 8) = pk1;
        *(u16x8*)&KLS(skey, sdb)     = pl0;
        *(u16x8*)&KLS(skey, sdb + 8) = pl1;
        __syncthreads();                 // B: K tile ready

        // ---- S phase ----
        f32x4 sacc[2];
#pragma unroll
        for (int nt = 0; nt < 2; ++nt) {
            f32x4 acc = (f32x4){0.f, 0.f, 0.f, 0.f};
#pragma unroll
            for (int kb = 0; kb < 4; ++kb) {
                const s16x8 bh_f = *(const s16x8*)&KHS(nt * 16 + lm, kb * 32 + lg * 8);
                const s16x8 bl_f = *(const s16x8*)&KLS(nt * 16 + lm, kb * 32 + lg * 8);
                acc = MFMA16(qh[kb], bh_f, acc);
                acc = MFMA16(ql[kb], bh_f, acc);
                acc = MFMA16(qh[kb], bl_f, acc);
            }
            sacc[nt] = acc;
        }

        // ---- online softmax, T13 defer-max (rows q=lg*4+r, cols key) ----
        float pmax[4];
#pragma unroll
        for (int r = 0; r < 4; ++r) {
            float v = fmaxf(sacc[0][r], sacc[1][r]);
            v = fmaxf(v, __shfl_xor(v, 1));
            v = fmaxf(v, __shfl_xor(v, 2));
            v = fmaxf(v, __shfl_xor(v, 4));
            v = fmaxf(v, __shfl_xor(v, 8));
            pmax[r] = v;
        }
        const bool grow = (pmax[0] - m[0] > 8.f) || (pmax[1] - m[1] > 8.f) ||
                          (pmax[2] - m[2] > 8.f) || (pmax[3] - m[3] > 8.f);
        if (__any(grow)) {               // rare after the first tile
#pragma unroll
            for (int r = 0; r < 4; ++r) {
                const float mnew = fmaxf(m[r], pmax[r]);
                const float corr = __expf(m[r] - mnew);
                m[r] = mnew;
                lsm[r] *= corr;
#pragma unroll
                for (int nt = 0; nt < 8; ++nt) o[nt][r] *= corr;
            }
        }
        float p0[4], p1[4];
#pragma unroll
        for (int r = 0; r < 4; ++r) {
            p0[r] = __expf(sacc[0][r] - m[r]);   // bounded by e^8
            p1[r] = __expf(sacc[1][r] - m[r]);
            float ls = p0[r] + p1[r];
            ls += __shfl_xor(ls, 1);
            ls += __shfl_xor(ls, 2);
            ls += __shfl_xor(ls, 4);
            ls += __shfl_xor(ls, 8);
            lsm[r] += ls;
        }

        __syncthreads();                 // C: all waves' K-reads done
        // V overlays K's LDS; Pb round-trip (wave-local) hides write latency
        *(u16x8*)&VSS(vdim, vkb)     = pv0;
        *(u16x8*)&VSS(vdim, vkb + 8) = pv1;

        // ---- write P to LDS (packed hi|lo, truncation split) ----
#pragma unroll
        for (int r = 0; r < 4; ++r) {
            const int row = woff + lg * 4 + r;
            const u16 h0 = f2bf_t(p0[r]);
            const u16 l0 = f2bf_t(p0[r] - bf2f(h0));
            Pb[row][lm] = (unsigned)h0 | ((unsigned)l0 << 16);
            const u16 h1 = f2bf_t(p1[r]);
            const u16 l1 = f2bf_t(p1[r] - bf2f(h1));
            Pb[row][16 + lm] = (unsigned)h1 | ((unsigned)l1 << 16);
        }

        // ---- read P fragments (A-layout: m=lm, k=lg*8+j), unpack hi/lo ----
        const u32x4 r0 = *(const u32x4*)&Pb[woff + lm][lg * 8];
        const u32x4 r1 = *(const u32x4*)&Pb[woff + lm][lg * 8 + 4];
        u32x4 phw, plw;
        phw[0] = (r0[0] & 0xffffu) | (r0[1] << 16);
        phw[1] = (r0[2] & 0xffffu) | (r0[3] << 16);
        phw[2] = (r1[0] & 0xffffu) | (r1[1] << 16);
        phw[3] = (r1[2] & 0xffffu) | (r1[3] << 16);
        plw[0] = (r0[0] >> 16) | (r0[1] & 0xffff0000u);
        plw[1] = (r0[2] >> 16) | (r0[3] & 0xffff0000u);
        plw[2] = (r1[0] >> 16) | (r1[1] & 0xffff0000u);
        plw[3] = (r1[2] >> 16) | (r1[3] & 0xffff0000u);
        const s16x8 pHf = __builtin_bit_cast(s16x8, phw);
        const s16x8 pLf = __builtin_bit_cast(s16x8, plw);

        __syncthreads();                 // D: V tile ready

        // ---- PV phase: O[q][d] += P * V ----
#pragma unroll
        for (int nt = 0; nt < 8; ++nt) {
            const s16x8 vf = *(const s16x8*)&VSS(nt * 16 + lm, lg * 8);
            o[nt] = MFMA16(pHf, vf, o[nt]);
            o[nt] = MFMA16(pLf, vf, o[nt]);
        }

        // rotate prefetch registers
        pk0 = nk0; pk1 = nk1; pl0 = nl0; pl1 = nl1; pv0 = nv0; pv1 = nv1;
    }
#undef KHS
#undef KLS
#undef VSS

    // ---- epilogue: divide by l, write O as bf16 hi/lo [b][s][h*128+d] ----
    const int bb = bh >> 4;
    const int hh = bh & 15;
    float inv[4];
#pragma unroll
    for (int r = 0; r < 4; ++r) inv[r] = 1.f / lsm[r];
#pragma unroll
    for (int nt = 0; nt < 8; ++nt) {
#pragma unroll
        for (int r = 0; r < 4; ++r) {
            const int qrow = q0 + woff + lg * 4 + r;
            const size_t idx =
                ((size_t)bb * SEQ + qrow) * DMODEL + hh * DK + nt * 16 + lm;
            const float y = o[nt][r] * inv[r];
            const u16 hb = f2bf_t(y);
            Ohi[idx] = hb;
            Olo[idx] = f2bf_t(y - bf2f(hb));
        }
    }
}

extern "C" void kernel_launch(void* const* d_in, const int* in_sizes, int n_in,
                              void* d_out, int out_size, void* d_ws, size_t ws_size,
                              hipStream_t stream) {
    const float* x  = (const float*)d_in[0];
    const float* wq = (const float*)d_in[1];
    const float* wk = (const float*)d_in[2];
    const float* wv = (const float*)d_in[3];
    const float* wo = (const float*)d_in[4];

    const size_t NE = (size_t)MROWS * DMODEL;    // 16,777,216
    const size_t WE = (size_t)DMODEL * DMODEL;   // 4,194,304

    // ws layout (u16 elems), total 7*NE u16 = 234.88 MB:
    //   [0,NE)        Qhi   (after attn: reused for Woh/Wol)
    //   [NE,2NE)      Qlo
    //   [2NE,3NE)     Khi
    //   [3NE,4NE)     Klo
    //   [4NE,5NE)     Vt
    //   [5NE,6.5NE)   Wqkv hi (3*WE) + lo (3*WE)  -- dead after qkv_proj
    //   [5NE,7NE)     Ohi, Olo                     -- written by attn
    // X split lives in d_out (dead until out_proj overwrites it).
    u16* Qhi = (u16*)d_ws;
    u16* Qlo = Qhi + NE;
    u16* Khi = Qhi + 2 * NE;
    u16* Klo = Qhi + 3 * NE;
    u16* Vt  = Qhi + 4 * NE;
    u16* Wqkvh = Qhi + 5 * NE;
    u16* Wqkvl = Wqkvh + 3 * WE;
    u16* Ohi = Qhi + 5 * NE;       // aliases Wqkv region (lifetimes disjoint)
    u16* Olo = Ohi + NE;
    u16* Woh = Qhi;                // aliases dead Qhi region (split after attn)
    u16* Wol = Woh + WE;
    u16* Xhi = (u16*)d_out;        // d_out scratch until out_proj
    u16* Xlo = Xhi + NE;

    dim3 blk(256);
    split_bf16_kernel<<<dim3(1024), blk, 0, stream>>>(x, Xhi, Xlo, (int)(NE / 8));
    split_bf16_kernel<<<dim3(512), blk, 0, stream>>>(wq, Wqkvh, Wqkvl, (int)(WE / 8));
    split_bf16_kernel<<<dim3(512), blk, 0, stream>>>(wk, Wqkvh + WE, Wqkvl + WE, (int)(WE / 8));
    split_bf16_kernel<<<dim3(512), blk, 0, stream>>>(wv, Wqkvh + 2 * WE, Wqkvl + 2 * WE, (int)(WE / 8));

    qkv_proj_mfma<<<dim3(48, 64), blk, 0, stream>>>(Xhi, Xlo, Wqkvh, Wqkvl,
                                                    Qhi, Qlo, Khi, Klo, Vt);
    attn_kernel<<<dim3(SEQ / 64, BATCH * NHEADS), blk, 0, stream>>>(
        Qhi, Qlo, Khi, Klo, Vt, Ohi, Olo);

    split_bf16_kernel<<<dim3(512), blk, 0, stream>>>(wo, Woh, Wol, (int)(WE / 8));
    out_proj_mfma<<<dim3(16, 64), blk, 0, stream>>>(Ohi, Olo, Woh, Wol, (float*)d_out);
}

// Round 5
// 1758.926 us; speedup vs baseline: 2.0115x; 2.0115x over previous
//
#include <hip/hip_runtime.h>
#include <math.h>

#define DMODEL 2048
#define NHEADS 16
#define DK     128
#define BATCH  4
#define SEQ    2048
#define MROWS  (BATCH*SEQ)   // 8192

typedef unsigned short u16;
typedef short s16x8 __attribute__((ext_vector_type(8)));
typedef u16   u16x4 __attribute__((ext_vector_type(4)));
typedef u16   u16x8 __attribute__((ext_vector_type(8)));
typedef float f32x4 __attribute__((ext_vector_type(4)));
typedef unsigned int u32x4 __attribute__((ext_vector_type(4)));

#define MFMA16(a, b, c) __builtin_amdgcn_mfma_f32_16x16x32_bf16((a), (b), (c), 0, 0, 0)

__device__ __forceinline__ u16 f2bf(float f) {       // RNE fp32 -> bf16 bits
    unsigned u = __builtin_bit_cast(unsigned, f);
    unsigned r = (u + 0x7fffu + ((u >> 16) & 1u)) >> 16;
    return (u16)r;
}
// truncating fp32 -> bf16 (1 op). Use ONLY where a lo-residual is also kept:
// hi = trunc(x), lo = trunc(x - hi) captures 16+ mantissa bits exactly.
__device__ __forceinline__ u16 f2bf_t(float f) {
    return (u16)(__builtin_bit_cast(unsigned, f) >> 16);
}
__device__ __forceinline__ float bf2f(u16 h) {
    unsigned u = ((unsigned)h) << 16;
    return __builtin_bit_cast(float, u);
}

// async global->LDS, 16B per lane. LDS dest must be linear in lane order.
__device__ __forceinline__ void gld_lds16(const u16* g, u16* l) {
    __builtin_amdgcn_global_load_lds(
        (const __attribute__((address_space(1))) unsigned int*)g,
        (__attribute__((address_space(3))) unsigned int*)l,
        16, 0, 0);
}

// ---------------------------------------------------------------------------
// fp32 -> (bf16 hi, bf16 lo) split, elementwise.
// ---------------------------------------------------------------------------
__global__ __launch_bounds__(256)
void split_bf16_kernel(const float* __restrict__ src,
                       u16* __restrict__ hi, u16* __restrict__ lo, int n8) {
    const int stride = gridDim.x * blockDim.x;
    for (int i = blockIdx.x * blockDim.x + threadIdx.x; i < n8; i += stride) {
        const float4 f0 = ((const float4*)src)[2 * i];
        const float4 f1 = ((const float4*)src)[2 * i + 1];
        const float f[8] = {f0.x, f0.y, f0.z, f0.w, f1.x, f1.y, f1.z, f1.w};
        u16x8 h8, l8;
#pragma unroll
        for (int j = 0; j < 8; ++j) {
            const u16 hb = f2bf_t(f[j]);
            h8[j] = hb;
            l8[j] = f2bf_t(f[j] - bf2f(hb));
        }
        ((u16x8*)hi)[i] = h8;
        ((u16x8*)lo)[i] = l8;
    }
}

// ---------------------------------------------------------------------------
// Split-bf16 MFMA NT-GEMM core: C[m,n] = sum_k A[m,k]*B[n,k] (~fp32 accuracy)
// via Ah*Bh + Al*Bh + Ah*Bl. 128x128 tile, BK=32, 4 waves (each 64x64).
// ---------------------------------------------------------------------------
__device__ __forceinline__ void gemm128_split_core(
        const u16* __restrict__ Ahg, const u16* __restrict__ Alg,
        const u16* __restrict__ Bhg, const u16* __restrict__ Blg,
        const int bm, const int bn, f32x4 (&acc)[4][4]) {
    __shared__ __align__(16) u16 Ah[128 * 32];
    __shared__ __align__(16) u16 Al[128 * 32];
    __shared__ __align__(16) u16 Bh[128 * 32];
    __shared__ __align__(16) u16 Bl[128 * 32];

    const int t    = threadIdx.x;
    const int lane = t & 63;
    const int wave = t >> 6;

    const int srow = t >> 2;            // 0..63
    const int skof = (t & 3) * 8;       // k elem offset 0,8,16,24
    const size_t ga0 = (size_t)(bm + srow) * DMODEL + skof;
    const size_t ga1 = (size_t)(bm + srow + 64) * DMODEL + skof;
    const size_t gb0 = (size_t)(bn + srow) * DMODEL + skof;
    const size_t gb1 = (size_t)(bn + srow + 64) * DMODEL + skof;
    const int l0 = srow * 32 + skof;
    const int l1 = l0 + 64 * 32;

    const int lm = lane & 15;
    const int lg = lane >> 4;
    const int wr = (wave >> 1) * 64;
    const int wc = (wave & 1) * 64;
    const int aoff = (wr + lm) * 32 + lg * 8;
    const int boff = (wc + lm) * 32 + lg * 8;

    for (int kt = 0; kt < DMODEL; kt += 32) {
        __syncthreads();
        gld_lds16(Ahg + ga0 + kt, &Ah[l0]);
        gld_lds16(Ahg + ga1 + kt, &Ah[l1]);
        gld_lds16(Alg + ga0 + kt, &Al[l0]);
        gld_lds16(Alg + ga1 + kt, &Al[l1]);
        gld_lds16(Bhg + gb0 + kt, &Bh[l0]);
        gld_lds16(Bhg + gb1 + kt, &Bh[l1]);
        gld_lds16(Blg + gb0 + kt, &Bl[l0]);
        gld_lds16(Blg + gb1 + kt, &Bl[l1]);
        __syncthreads();

        s16x8 af[4], alf[4];
#pragma unroll
        for (int i = 0; i < 4; ++i) {
            af[i]  = *(const s16x8*)&Ah[aoff + i * 16 * 32];
            alf[i] = *(const s16x8*)&Al[aoff + i * 16 * 32];
        }
#pragma unroll
        for (int j = 0; j < 4; ++j) {
            const s16x8 bf  = *(const s16x8*)&Bh[boff + j * 16 * 32];
            const s16x8 blf = *(const s16x8*)&Bl[boff + j * 16 * 32];
#pragma unroll
            for (int i = 0; i < 4; ++i) {
                acc[i][j] = MFMA16(af[i],  bf,  acc[i][j]);
                acc[i][j] = MFMA16(alf[i], bf,  acc[i][j]);
                acc[i][j] = MFMA16(af[i],  blf, acc[i][j]);
            }
        }
    }
}

// QKV projection (MFMA). Q,K -> bf16 hi/lo [BH,S,128] (Q pre-scaled by
// 1/sqrt(dk)). V -> bf16 TRANSPOSED [BH,128,S].
__global__ __launch_bounds__(256)
void qkv_proj_mfma(const u16* __restrict__ Xhi, const u16* __restrict__ Xlo,
                   const u16* __restrict__ Wh,  const u16* __restrict__ Wl,
                   u16* __restrict__ Qhi, u16* __restrict__ Qlo,
                   u16* __restrict__ Khi, u16* __restrict__ Klo,
                   u16* __restrict__ Vt) {
    const int g  = blockIdx.x >> 4;          // 0=Q 1=K 2=V
    const int nb = blockIdx.x & 15;          // head
    const int bm = blockIdx.y * 128;
    const size_t WE = (size_t)DMODEL * DMODEL;

    f32x4 acc[4][4] = {};
    gemm128_split_core(Xhi, Xlo, Wh + g * WE, Wl + g * WE, bm, nb * 128, acc);

    const int lane = threadIdx.x & 63;
    const int wave = threadIdx.x >> 6;
    const int lm = lane & 15;
    const int lg = lane >> 4;
    const int wr = (wave >> 1) * 64;
    const int wc = (wave & 1) * 64;

    if (g < 2) {
        u16* hiP = (g == 0) ? Qhi : Khi;
        u16* loP = (g == 0) ? Qlo : Klo;
        const float sc = (g == 0) ? 0.08838834764831845f : 1.0f;
#pragma unroll
        for (int i = 0; i < 4; ++i) {
#pragma unroll
            for (int r = 0; r < 4; ++r) {
                const int s  = bm + wr + i * 16 + lg * 4 + r;
                const int bb = s >> 11;
                const size_t base =
                    ((size_t)(bb * NHEADS + nb) * SEQ + (s & 2047)) * DK + wc + lm;
#pragma unroll
                for (int j = 0; j < 4; ++j) {
                    const float y = acc[i][j][r] * sc;
                    const u16 hb = f2bf_t(y);
                    hiP[base + j * 16] = hb;
                    loP[base + j * 16] = f2bf_t(y - bf2f(hb));
                }
            }
        }
    } else {
        // V transposed: Vt[bh][d][s]. Single bf16 -> keep RNE (dominant
        // error term of the whole pipeline).
#pragma unroll
        for (int i = 0; i < 4; ++i) {
            const int s0 = bm + wr + i * 16 + lg * 4;
            const int bb = s0 >> 11;
            const int ss = s0 & 2047;
            const size_t rowb = (size_t)(bb * NHEADS + nb) * DK;
#pragma unroll
            for (int j = 0; j < 4; ++j) {
                u16x4 v;
#pragma unroll
                for (int r = 0; r < 4; ++r) v[r] = f2bf(acc[i][j][r]);
                *(u16x4*)(Vt + (rowb + wc + j * 16 + lm) * SEQ + ss) = v;
            }
        }
    }
}

// out = O @ wo^T (MFMA split), fp32 output.
__global__ __launch_bounds__(256)
void out_proj_mfma(const u16* __restrict__ Ohi, const u16* __restrict__ Olo,
                   const u16* __restrict__ Woh, const u16* __restrict__ Wol,
                   float* __restrict__ out) {
    const int bn = blockIdx.x * 128;
    const int bm = blockIdx.y * 128;
    f32x4 acc[4][4] = {};
    gemm128_split_core(Ohi, Olo, Woh, Wol, bm, bn, acc);

    const int lane = threadIdx.x & 63;
    const int wave = threadIdx.x >> 6;
    const int lm = lane & 15;
    const int lg = lane >> 4;
    const int wr = (wave >> 1) * 64;
    const int wc = (wave & 1) * 64;
#pragma unroll
    for (int i = 0; i < 4; ++i) {
#pragma unroll
        for (int r = 0; r < 4; ++r) {
            const int row = bm + wr + i * 16 + lg * 4 + r;
            float* dst = out + (size_t)row * DMODEL + bn + wc + lm;
#pragma unroll
            for (int j = 0; j < 4; ++j) dst[j * 16] = acc[i][j][r];
        }
    }
}

// ---------------------------------------------------------------------------
// MFMA flash attention, split-bf16, K/V LDS overlay (26624B -> 6 blocks/CU),
// T13 defer-max, T14 register prefetch, T1 XCD swizzle.
// launch_bounds: (256,4) -> VGPR cap 128. Round-4 lesson: (256,6) capped
// VGPRs at 85 < ~110 live state -> accumulator spill to scratch (11.8 GB/
// dispatch, 4.2x slower). The 2nd arg only GUARANTEES occupancy by capping
// registers; with VGPR<=85 natural allocation the LDS overlay alone yields
// 6 blocks/CU.
// ---------------------------------------------------------------------------
__global__ __launch_bounds__(256, 4)
void attn_kernel(const u16* __restrict__ Qhi, const u16* __restrict__ Qlo,
                 const u16* __restrict__ KhiG, const u16* __restrict__ KloG,
                 const u16* __restrict__ VtG,
                 u16* __restrict__ Ohi, u16* __restrict__ Olo) {
    // K-phase: Khs = KV[0..4351] ([32][136]), Kls = KV[4352..8703]
    // V-phase: Vs overlays KV[0..5119] ([128][40])
    __shared__ __align__(16) u16 KV[2 * 32 * 136];
    __shared__ unsigned int Pb[64][36];  // packed (phi | plo<<16)
#define KHS(r, c) KV[(r) * 136 + (c)]
#define KLS(r, c) KV[4352 + (r) * 136 + (c)]
#define VSS(d, k) KV[(d) * 40 + (k)]

    // XCD-bijective swizzle: 2048 blocks, 8 XCDs, 256 per XCD.
    const int idlin = blockIdx.y * gridDim.x + blockIdx.x;   // 0..2047
    const int swz   = (idlin & 7) * 256 + (idlin >> 3);
    const int bh    = swz >> 5;
    const int q0    = (swz & 31) * 64;

    const int t  = threadIdx.x;
    const int l  = t & 63;
    const int w  = t >> 6;
    const int lm = l & 15;       // "m/n" lane index
    const int lg = l >> 4;       // k-quad
    const int woff = w * 16;

    // ---- load Q fragments (A-layout: m=lm, k=kb*32+lg*8+j) ----
    s16x8 qh[4], ql[4];
    {
        const size_t qrow = (size_t)bh * SEQ + q0 + woff + lm;
#pragma unroll
        for (int kb = 0; kb < 4; ++kb) {
            const size_t off = qrow * DK + kb * 32 + lg * 8;
            qh[kb] = *(const s16x8*)(Qhi + off);
            ql[kb] = *(const s16x8*)(Qlo + off);
        }
    }

    f32x4 o[8];
#pragma unroll
    for (int nt = 0; nt < 8; ++nt) o[nt] = (f32x4){0.f, 0.f, 0.f, 0.f};
    float m[4] = {-1e30f, -1e30f, -1e30f, -1e30f};
    float lsm[4] = {0.f, 0.f, 0.f, 0.f};

    // staging indices
    const int skey = t >> 3;            // 0..31
    const int sdb  = (t & 7) * 16;      // dim base for K staging
    const int vdim = t >> 1;            // 0..127
    const int vkb  = (t & 1) * 16;      // key base for V staging
    const u16* Kh_base = KhiG + ((size_t)bh * SEQ + skey) * DK + sdb;
    const u16* Kl_base = KloG + ((size_t)bh * SEQ + skey) * DK + sdb;
    const u16* Vt_base = VtG + ((size_t)bh * DK + vdim) * SEQ + vkb;

    // ---- T14 prologue: prefetch tile 0 into registers ----
    u16x8 pk0 = *(const u16x8*)(Kh_base);
    u16x8 pk1 = *(const u16x8*)(Kh_base + 8);
    u16x8 pl0 = *(const u16x8*)(Kl_base);
    u16x8 pl1 = *(const u16x8*)(Kl_base + 8);
    u16x8 pv0 = *(const u16x8*)(Vt_base);
    u16x8 pv1 = *(const u16x8*)(Vt_base + 8);

    for (int kt = 0; kt < SEQ; kt += 32) {
        // issue next tile's loads NOW; latency spans barriers + compute.
        const int ktn = (kt + 32 < SEQ) ? kt + 32 : 0;
        const u16* khn = Kh_base + (size_t)ktn * DK;
        const u16* kln = Kl_base + (size_t)ktn * DK;
        const u16* vpn = Vt_base + ktn;
        const u16x8 nk0 = *(const u16x8*)khn;
        const u16x8 nk1 = *(const u16x8*)(khn + 8);
        const u16x8 nl0 = *(const u16x8*)kln;
        const u16x8 nl1 = *(const u16x8*)(kln + 8);
        const u16x8 nv0 = *(const u16x8*)vpn;
        const u16x8 nv1 = *(const u16x8*)(vpn + 8);

        __syncthreads();                 // A: prev PV done -> KV writable
        *(u16x8*)&KHS(skey, sdb)     = pk0;
        *(u16x8*)&KHS(skey, sdb + 8) = pk1;
        *(u16x8*)&KLS(skey, sdb)     = pl0;
        *(u16x8*)&KLS(skey, sdb + 8) = pl1;
        __syncthreads();                 // B: K tile ready

        // ---- S phase ----
        f32x4 sacc[2];
#pragma unroll
        for (int nt = 0; nt < 2; ++nt) {
            f32x4 acc = (f32x4){0.f, 0.f, 0.f, 0.f};
#pragma unroll
            for (int kb = 0; kb < 4; ++kb) {
                const s16x8 bh_f = *(const s16x8*)&KHS(nt * 16 + lm, kb * 32 + lg * 8);
                const s16x8 bl_f = *(const s16x8*)&KLS(nt * 16 + lm, kb * 32 + lg * 8);
                acc = MFMA16(qh[kb], bh_f, acc);
                acc = MFMA16(ql[kb], bh_f, acc);
                acc = MFMA16(qh[kb], bl_f, acc);
            }
            sacc[nt] = acc;
        }

        // ---- online softmax, T13 defer-max (rows q=lg*4+r, cols key) ----
        float pmax[4];
#pragma unroll
        for (int r = 0; r < 4; ++r) {
            float v = fmaxf(sacc[0][r], sacc[1][r]);
            v = fmaxf(v, __shfl_xor(v, 1));
            v = fmaxf(v, __shfl_xor(v, 2));
            v = fmaxf(v, __shfl_xor(v, 4));
            v = fmaxf(v, __shfl_xor(v, 8));
            pmax[r] = v;
        }
        const bool grow = (pmax[0] - m[0] > 8.f) || (pmax[1] - m[1] > 8.f) ||
                          (pmax[2] - m[2] > 8.f) || (pmax[3] - m[3] > 8.f);
        if (__any(grow)) {               // rare after the first tile
#pragma unroll
            for (int r = 0; r < 4; ++r) {
                const float mnew = fmaxf(m[r], pmax[r]);
                const float corr = __expf(m[r] - mnew);
                m[r] = mnew;
                lsm[r] *= corr;
#pragma unroll
                for (int nt = 0; nt < 8; ++nt) o[nt][r] *= corr;
            }
        }
        float p0[4], p1[4];
#pragma unroll
        for (int r = 0; r < 4; ++r) {
            p0[r] = __expf(sacc[0][r] - m[r]);   // bounded by e^8
            p1[r] = __expf(sacc[1][r] - m[r]);
            float ls = p0[r] + p1[r];
            ls += __shfl_xor(ls, 1);
            ls += __shfl_xor(ls, 2);
            ls += __shfl_xor(ls, 4);
            ls += __shfl_xor(ls, 8);
            lsm[r] += ls;
        }

        __syncthreads();                 // C: all waves' K-reads done
        // V overlays K's LDS; Pb round-trip (wave-local) hides write latency
        *(u16x8*)&VSS(vdim, vkb)     = pv0;
        *(u16x8*)&VSS(vdim, vkb + 8) = pv1;

        // ---- write P to LDS (packed hi|lo, truncation split) ----
#pragma unroll
        for (int r = 0; r < 4; ++r) {
            const int row = woff + lg * 4 + r;
            const u16 h0 = f2bf_t(p0[r]);
            const u16 l0 = f2bf_t(p0[r] - bf2f(h0));
            Pb[row][lm] = (unsigned)h0 | ((unsigned)l0 << 16);
            const u16 h1 = f2bf_t(p1[r]);
            const u16 l1 = f2bf_t(p1[r] - bf2f(h1));
            Pb[row][16 + lm] = (unsigned)h1 | ((unsigned)l1 << 16);
        }

        // ---- read P fragments (A-layout: m=lm, k=lg*8+j), unpack hi/lo ----
        const u32x4 r0 = *(const u32x4*)&Pb[woff + lm][lg * 8];
        const u32x4 r1 = *(const u32x4*)&Pb[woff + lm][lg * 8 + 4];
        u32x4 phw, plw;
        phw[0] = (r0[0] & 0xffffu) | (r0[1] << 16);
        phw[1] = (r0[2] & 0xffffu) | (r0[3] << 16);
        phw[2] = (r1[0] & 0xffffu) | (r1[1] << 16);
        phw[3] = (r1[2] & 0xffffu) | (r1[3] << 16);
        plw[0] = (r0[0] >> 16) | (r0[1] & 0xffff0000u);
        plw[1] = (r0[2] >> 16) | (r0[3] & 0xffff0000u);
        plw[2] = (r1[0] >> 16) | (r1[1] & 0xffff0000u);
        plw[3] = (r1[2] >> 16) | (r1[3] & 0xffff0000u);
        const s16x8 pHf = __builtin_bit_cast(s16x8, phw);
        const s16x8 pLf = __builtin_bit_cast(s16x8, plw);

        __syncthreads();                 // D: V tile ready

        // ---- PV phase: O[q][d] += P * V ----
#pragma unroll
        for (int nt = 0; nt < 8; ++nt) {
            const s16x8 vf = *(const s16x8*)&VSS(nt * 16 + lm, lg * 8);
            o[nt] = MFMA16(pHf, vf, o[nt]);
            o[nt] = MFMA16(pLf, vf, o[nt]);
        }

        // rotate prefetch registers
        pk0 = nk0; pk1 = nk1; pl0 = nl0; pl1 = nl1; pv0 = nv0; pv1 = nv1;
    }
#undef KHS
#undef KLS
#undef VSS

    // ---- epilogue: divide by l, write O as bf16 hi/lo [b][s][h*128+d] ----
    const int bb = bh >> 4;
    const int hh = bh & 15;
    float inv[4];
#pragma unroll
    for (int r = 0; r < 4; ++r) inv[r] = 1.f / lsm[r];
#pragma unroll
    for (int nt = 0; nt < 8; ++nt) {
#pragma unroll
        for (int r = 0; r < 4; ++r) {
            const int qrow = q0 + woff + lg * 4 + r;
            const size_t idx =
                ((size_t)bb * SEQ + qrow) * DMODEL + hh * DK + nt * 16 + lm;
            const float y = o[nt][r] * inv[r];
            const u16 hb = f2bf_t(y);
            Ohi[idx] = hb;
            Olo[idx] = f2bf_t(y - bf2f(hb));
        }
    }
}

extern "C" void kernel_launch(void* const* d_in, const int* in_sizes, int n_in,
                              void* d_out, int out_size, void* d_ws, size_t ws_size,
                              hipStream_t stream) {
    const float* x  = (const float*)d_in[0];
    const float* wq = (const float*)d_in[1];
    const float* wk = (const float*)d_in[2];
    const float* wv = (const float*)d_in[3];
    const float* wo = (const float*)d_in[4];

    const size_t NE = (size_t)MROWS * DMODEL;    // 16,777,216
    const size_t WE = (size_t)DMODEL * DMODEL;   // 4,194,304

    // ws layout (u16 elems), total 7*NE u16 = 234.88 MB:
    //   [0,NE)        Qhi   (after attn: reused for Woh/Wol)
    //   [NE,2NE)      Qlo
    //   [2NE,3NE)     Khi
    //   [3NE,4NE)     Klo
    //   [4NE,5NE)     Vt
    //   [5NE,6.5NE)   Wqkv hi (3*WE) + lo (3*WE)  -- dead after qkv_proj
    //   [5NE,7NE)     Ohi, Olo                     -- written by attn
    // X split lives in d_out (dead until out_proj overwrites it).
    u16* Qhi = (u16*)d_ws;
    u16* Qlo = Qhi + NE;
    u16* Khi = Qhi + 2 * NE;
    u16* Klo = Qhi + 3 * NE;
    u16* Vt  = Qhi + 4 * NE;
    u16* Wqkvh = Qhi + 5 * NE;
    u16* Wqkvl = Wqkvh + 3 * WE;
    u16* Ohi = Qhi + 5 * NE;       // aliases Wqkv region (lifetimes disjoint)
    u16* Olo = Ohi + NE;
    u16* Woh = Qhi;                // aliases dead Qhi region (split after attn)
    u16* Wol = Woh + WE;
    u16* Xhi = (u16*)d_out;        // d_out scratch until out_proj
    u16* Xlo = Xhi + NE;

    dim3 blk(256);
    split_bf16_kernel<<<dim3(1024), blk, 0, stream>>>(x, Xhi, Xlo, (int)(NE / 8));
    split_bf16_kernel<<<dim3(512), blk, 0, stream>>>(wq, Wqkvh, Wqkvl, (int)(WE / 8));
    split_bf16_kernel<<<dim3(512), blk, 0, stream>>>(wk, Wqkvh + WE, Wqkvl + WE, (int)(WE / 8));
    split_bf16_kernel<<<dim3(512), blk, 0, stream>>>(wv, Wqkvh + 2 * WE, Wqkvl + 2 * WE, (int)(WE / 8));

    qkv_proj_mfma<<<dim3(48, 64), blk, 0, stream>>>(Xhi, Xlo, Wqkvh, Wqkvl,
                                                    Qhi, Qlo, Khi, Klo, Vt);
    attn_kernel<<<dim3(SEQ / 64, BATCH * NHEADS), blk, 0, stream>>>(
        Qhi, Qlo, Khi, Klo, Vt, Ohi, Olo);

    split_bf16_kernel<<<dim3(512), blk, 0, stream>>>(wo, Woh, Wol, (int)(WE / 8));
    out_proj_mfma<<<dim3(16, 64), blk, 0, stream>>>(Ohi, Olo, Woh, Wol, (float*)d_out);
}

// Round 6
// 1356.820 us; speedup vs baseline: 2.6076x; 1.2964x over previous
//
#include <hip/hip_runtime.h>
#include <math.h>

#define DMODEL 2048
#define NHEADS 16
#define DK     128
#define BATCH  4
#define SEQ    2048
#define MROWS  (BATCH*SEQ)   // 8192

typedef unsigned short u16;
typedef short s16x8 __attribute__((ext_vector_type(8)));
typedef u16   u16x4 __attribute__((ext_vector_type(4)));
typedef u16   u16x8 __attribute__((ext_vector_type(8)));
typedef float f32x4 __attribute__((ext_vector_type(4)));
typedef unsigned int u32x2 __attribute__((ext_vector_type(2)));
typedef unsigned int u32x4 __attribute__((ext_vector_type(4)));

#define MFMA16(a, b, c) __builtin_amdgcn_mfma_f32_16x16x32_bf16((a), (b), (c), 0, 0, 0)

__device__ __forceinline__ u16 f2bf(float f) {       // RNE fp32 -> bf16 bits
    unsigned u = __builtin_bit_cast(unsigned, f);
    unsigned r = (u + 0x7fffu + ((u >> 16) & 1u)) >> 16;
    return (u16)r;
}
// truncating fp32 -> bf16 (1 op). Use ONLY where a lo-residual is also kept:
// hi = trunc(x), lo = trunc(x - hi) captures 16+ mantissa bits exactly.
__device__ __forceinline__ u16 f2bf_t(float f) {
    return (u16)(__builtin_bit_cast(unsigned, f) >> 16);
}
__device__ __forceinline__ float bf2f(u16 h) {
    unsigned u = ((unsigned)h) << 16;
    return __builtin_bit_cast(float, u);
}

// async global->LDS, 16B per lane. LDS dest must be linear in lane order.
__device__ __forceinline__ void gld_lds16(const u16* g, u16* l) {
    __builtin_amdgcn_global_load_lds(
        (const __attribute__((address_space(1))) unsigned int*)g,
        (__attribute__((address_space(3))) unsigned int*)l,
        16, 0, 0);
}

// ---------------------------------------------------------------------------
// fp32 -> (bf16 hi, bf16 lo) split, elementwise.
// ---------------------------------------------------------------------------
__global__ __launch_bounds__(256)
void split_bf16_kernel(const float* __restrict__ src,
                       u16* __restrict__ hi, u16* __restrict__ lo, int n8) {
    const int stride = gridDim.x * blockDim.x;
    for (int i = blockIdx.x * blockDim.x + threadIdx.x; i < n8; i += stride) {
        const float4 f0 = ((const float4*)src)[2 * i];
        const float4 f1 = ((const float4*)src)[2 * i + 1];
        const float f[8] = {f0.x, f0.y, f0.z, f0.w, f1.x, f1.y, f1.z, f1.w};
        u16x8 h8, l8;
#pragma unroll
        for (int j = 0; j < 8; ++j) {
            const u16 hb = f2bf_t(f[j]);
            h8[j] = hb;
            l8[j] = f2bf_t(f[j] - bf2f(hb));
        }
        ((u16x8*)hi)[i] = h8;
        ((u16x8*)lo)[i] = l8;
    }
}

// ---------------------------------------------------------------------------
// Split-bf16 MFMA NT-GEMM core: C[m,n] = sum_k A[m,k]*B[n,k] (~fp32 accuracy)
// via Ah*Bh + Al*Bh + Ah*Bl. 128x128 tile, BK=32, 4 waves (each 64x64).
// ---------------------------------------------------------------------------
__device__ __forceinline__ void gemm128_split_core(
        const u16* __restrict__ Ahg, const u16* __restrict__ Alg,
        const u16* __restrict__ Bhg, const u16* __restrict__ Blg,
        const int bm, const int bn, f32x4 (&acc)[4][4]) {
    __shared__ __align__(16) u16 Ah[128 * 32];
    __shared__ __align__(16) u16 Al[128 * 32];
    __shared__ __align__(16) u16 Bh[128 * 32];
    __shared__ __align__(16) u16 Bl[128 * 32];

    const int t    = threadIdx.x;
    const int lane = t & 63;
    const int wave = t >> 6;

    const int srow = t >> 2;            // 0..63
    const int skof = (t & 3) * 8;       // k elem offset 0,8,16,24
    const size_t ga0 = (size_t)(bm + srow) * DMODEL + skof;
    const size_t ga1 = (size_t)(bm + srow + 64) * DMODEL + skof;
    const size_t gb0 = (size_t)(bn + srow) * DMODEL + skof;
    const size_t gb1 = (size_t)(bn + srow + 64) * DMODEL + skof;
    const int l0 = srow * 32 + skof;
    const int l1 = l0 + 64 * 32;

    const int lm = lane & 15;
    const int lg = lane >> 4;
    const int wr = (wave >> 1) * 64;
    const int wc = (wave & 1) * 64;
    const int aoff = (wr + lm) * 32 + lg * 8;
    const int boff = (wc + lm) * 32 + lg * 8;

    for (int kt = 0; kt < DMODEL; kt += 32) {
        __syncthreads();
        gld_lds16(Ahg + ga0 + kt, &Ah[l0]);
        gld_lds16(Ahg + ga1 + kt, &Ah[l1]);
        gld_lds16(Alg + ga0 + kt, &Al[l0]);
        gld_lds16(Alg + ga1 + kt, &Al[l1]);
        gld_lds16(Bhg + gb0 + kt, &Bh[l0]);
        gld_lds16(Bhg + gb1 + kt, &Bh[l1]);
        gld_lds16(Blg + gb0 + kt, &Bl[l0]);
        gld_lds16(Blg + gb1 + kt, &Bl[l1]);
        __syncthreads();

        s16x8 af[4], alf[4];
#pragma unroll
        for (int i = 0; i < 4; ++i) {
            af[i]  = *(const s16x8*)&Ah[aoff + i * 16 * 32];
            alf[i] = *(const s16x8*)&Al[aoff + i * 16 * 32];
        }
#pragma unroll
        for (int j = 0; j < 4; ++j) {
            const s16x8 bf  = *(const s16x8*)&Bh[boff + j * 16 * 32];
            const s16x8 blf = *(const s16x8*)&Bl[boff + j * 16 * 32];
#pragma unroll
            for (int i = 0; i < 4; ++i) {
                acc[i][j] = MFMA16(af[i],  bf,  acc[i][j]);
                acc[i][j] = MFMA16(alf[i], bf,  acc[i][j]);
                acc[i][j] = MFMA16(af[i],  blf, acc[i][j]);
            }
        }
    }
}

// QKV projection (MFMA). Q,K -> bf16 hi/lo [BH,S,128] (Q pre-scaled by
// 1/sqrt(dk)). V -> bf16 TRANSPOSED [BH,128,S].
__global__ __launch_bounds__(256)
void qkv_proj_mfma(const u16* __restrict__ Xhi, const u16* __restrict__ Xlo,
                   const u16* __restrict__ Wh,  const u16* __restrict__ Wl,
                   u16* __restrict__ Qhi, u16* __restrict__ Qlo,
                   u16* __restrict__ Khi, u16* __restrict__ Klo,
                   u16* __restrict__ Vt) {
    const int g  = blockIdx.x >> 4;          // 0=Q 1=K 2=V
    const int nb = blockIdx.x & 15;          // head
    const int bm = blockIdx.y * 128;
    const size_t WE = (size_t)DMODEL * DMODEL;

    f32x4 acc[4][4] = {};
    gemm128_split_core(Xhi, Xlo, Wh + g * WE, Wl + g * WE, bm, nb * 128, acc);

    const int lane = threadIdx.x & 63;
    const int wave = threadIdx.x >> 6;
    const int lm = lane & 15;
    const int lg = lane >> 4;
    const int wr = (wave >> 1) * 64;
    const int wc = (wave & 1) * 64;

    if (g < 2) {
        u16* hiP = (g == 0) ? Qhi : Khi;
        u16* loP = (g == 0) ? Qlo : Klo;
        const float sc = (g == 0) ? 0.08838834764831845f : 1.0f;
#pragma unroll
        for (int i = 0; i < 4; ++i) {
#pragma unroll
            for (int r = 0; r < 4; ++r) {
                const int s  = bm + wr + i * 16 + lg * 4 + r;
                const int bb = s >> 11;
                const size_t base =
                    ((size_t)(bb * NHEADS + nb) * SEQ + (s & 2047)) * DK + wc + lm;
#pragma unroll
                for (int j = 0; j < 4; ++j) {
                    const float y = acc[i][j][r] * sc;
                    const u16 hb = f2bf_t(y);
                    hiP[base + j * 16] = hb;
                    loP[base + j * 16] = f2bf_t(y - bf2f(hb));
                }
            }
        }
    } else {
        // V transposed: Vt[bh][d][s]. Single bf16 -> keep RNE (dominant
        // error term of the whole pipeline).
#pragma unroll
        for (int i = 0; i < 4; ++i) {
            const int s0 = bm + wr + i * 16 + lg * 4;
            const int bb = s0 >> 11;
            const int ss = s0 & 2047;
            const size_t rowb = (size_t)(bb * NHEADS + nb) * DK;
#pragma unroll
            for (int j = 0; j < 4; ++j) {
                u16x4 v;
#pragma unroll
                for (int r = 0; r < 4; ++r) v[r] = f2bf(acc[i][j][r]);
                *(u16x4*)(Vt + (rowb + wc + j * 16 + lm) * SEQ + ss) = v;
            }
        }
    }
}

// out = O @ wo^T (MFMA split), fp32 output.
__global__ __launch_bounds__(256)
void out_proj_mfma(const u16* __restrict__ Ohi, const u16* __restrict__ Olo,
                   const u16* __restrict__ Woh, const u16* __restrict__ Wol,
                   float* __restrict__ out) {
    const int bn = blockIdx.x * 128;
    const int bm = blockIdx.y * 128;
    f32x4 acc[4][4] = {};
    gemm128_split_core(Ohi, Olo, Woh, Wol, bm, bn, acc);

    const int lane = threadIdx.x & 63;
    const int wave = threadIdx.x >> 6;
    const int lm = lane & 15;
    const int lg = lane >> 4;
    const int wr = (wave >> 1) * 64;
    const int wc = (wave & 1) * 64;
#pragma unroll
    for (int i = 0; i < 4; ++i) {
#pragma unroll
        for (int r = 0; r < 4; ++r) {
            const int row = bm + wr + i * 16 + lg * 4 + r;
            float* dst = out + (size_t)row * DMODEL + bn + wc + lm;
#pragma unroll
            for (int j = 0; j < 4; ++j) dst[j * 16] = acc[i][j][r];
        }
    }
}

// ---------------------------------------------------------------------------
// MFMA flash attention, split-bf16, SWAPPED QK^T (T12 core idea).
// S^T = mfma(K_frag, Q_frag): A/B fragment layouts are identical in form, so
// the swap is an argument swap with the SAME LDS reads. Result: each lane
// holds 8 scores (keys lg*4+r and 16+lg*4+r) for ONE query (lm):
//   - row-softmax reduce = 2 shuffles (xor16, xor32) instead of 8/row x 4 rows
//   - softmax state m/lsm = 2 scalars/lane
//   - P -> PV A-fragment via tiny wave-local LDS bounce (2 b128 writes +
//     4 b64 reads, no pack/unpack words): key 8*lg+j for query lm comes from
//     lane ((2lg + j/4)&3)*16+lm, word (j&3)/2 + (lg<2 ? 0 : 2).
// Round-4/5 lesson: unified VGPR+AGPR file binds occupancy at 4 waves/SIMD;
// LDS overlays bought nothing and spilled. Back to 2-barrier staging (653us
// structure), (256,4).
// ---------------------------------------------------------------------------
__global__ __launch_bounds__(256, 4)
void attn_kernel(const u16* __restrict__ Qhi, const u16* __restrict__ Qlo,
                 const u16* __restrict__ KhiG, const u16* __restrict__ KloG,
                 const u16* __restrict__ VtG,
                 u16* __restrict__ Ohi, u16* __restrict__ Olo) {
    __shared__ __align__(16) u16 Khs[32][136];
    __shared__ __align__(16) u16 Kls[32][136];
    __shared__ __align__(16) u16 Vs[128][40];          // [dim][key]
    __shared__ __align__(16) unsigned int Pw[256][12]; // per-lane P words (4 hi, 4 lo, 4 pad)

    // XCD-bijective swizzle: 2048 blocks, 8 XCDs, 256 per XCD.
    const int idlin = blockIdx.y * gridDim.x + blockIdx.x;   // 0..2047
    const int swz   = (idlin & 7) * 256 + (idlin >> 3);
    const int bh    = swz >> 5;
    const int q0    = (swz & 31) * 64;

    const int t  = threadIdx.x;
    const int l  = t & 63;
    const int w  = t >> 6;
    const int lm = l & 15;       // query index (this lane's query)
    const int lg = l >> 4;       // k-quad
    const int woff = w * 16;

    // ---- load Q fragments (B-operand; layout m/n=lm, k=kb*32+lg*8+j) ----
    s16x8 qh[4], ql[4];
    {
        const size_t qrow = (size_t)bh * SEQ + q0 + woff + lm;
#pragma unroll
        for (int kb = 0; kb < 4; ++kb) {
            const size_t off = qrow * DK + kb * 32 + lg * 8;
            qh[kb] = *(const s16x8*)(Qhi + off);
            ql[kb] = *(const s16x8*)(Qlo + off);
        }
    }

    f32x4 o[8];
#pragma unroll
    for (int nt = 0; nt < 8; ++nt) o[nt] = (f32x4){0.f, 0.f, 0.f, 0.f};
    float mrun = -1e30f;
    float lsm  = 0.f;

    // staging indices (round-3 structure)
    const int skey = t >> 3;            // 0..31
    const int sdb  = (t & 7) * 16;      // dim base for K staging
    const int vdim = t >> 1;            // 0..127
    const int vkb  = (t & 1) * 16;      // key base for V staging
    const u16* Kh_base = KhiG + ((size_t)bh * SEQ + skey) * DK + sdb;
    const u16* Kl_base = KloG + ((size_t)bh * SEQ + skey) * DK + sdb;
    const u16* Vt_base = VtG + ((size_t)bh * DK + vdim) * SEQ + vkb;

    // P-bounce addressing (wave-local rows of Pw)
    const int prowA = w * 64 + ((2 * lg) & 3) * 16 + lm;
    const int prowB = w * 64 + ((2 * lg + 1) & 3) * 16 + lm;
    const int pcol  = (lg < 2) ? 0 : 2;

    // ---- prologue: prefetch tile 0 into registers ----
    u16x8 pk0 = *(const u16x8*)(Kh_base);
    u16x8 pk1 = *(const u16x8*)(Kh_base + 8);
    u16x8 pl0 = *(const u16x8*)(Kl_base);
    u16x8 pl1 = *(const u16x8*)(Kl_base + 8);
    u16x8 pv0 = *(const u16x8*)(Vt_base);
    u16x8 pv1 = *(const u16x8*)(Vt_base + 8);

    for (int kt = 0; kt < SEQ; kt += 32) {
        // issue next tile's loads NOW; latency spans barrier + compute.
        const int ktn = (kt + 32 < SEQ) ? kt + 32 : 0;
        const u16* khn = Kh_base + (size_t)ktn * DK;
        const u16* kln = Kl_base + (size_t)ktn * DK;
        const u16* vpn = Vt_base + ktn;
        const u16x8 nk0 = *(const u16x8*)khn;
        const u16x8 nk1 = *(const u16x8*)(khn + 8);
        const u16x8 nl0 = *(const u16x8*)kln;
        const u16x8 nl1 = *(const u16x8*)(kln + 8);
        const u16x8 nv0 = *(const u16x8*)vpn;
        const u16x8 nv1 = *(const u16x8*)(vpn + 8);

        __syncthreads();                 // A: all waves done reading prev tile
        *(u16x8*)&Khs[skey][sdb]     = pk0;
        *(u16x8*)&Khs[skey][sdb + 8] = pk1;
        *(u16x8*)&Kls[skey][sdb]     = pl0;
        *(u16x8*)&Kls[skey][sdb + 8] = pl1;
        *(u16x8*)&Vs[vdim][vkb]      = pv0;
        *(u16x8*)&Vs[vdim][vkb + 8]  = pv1;
        __syncthreads();                 // B: tile ready

        // ---- S^T phase: mfma(K, Q) -> lane holds 8 keys x 1 query ----
        f32x4 sacc[2];
#pragma unroll
        for (int nt = 0; nt < 2; ++nt) {
            f32x4 acc = (f32x4){0.f, 0.f, 0.f, 0.f};
#pragma unroll
            for (int kb = 0; kb < 4; ++kb) {
                const s16x8 kh_f = *(const s16x8*)&Khs[nt * 16 + lm][kb * 32 + lg * 8];
                const s16x8 kl_f = *(const s16x8*)&Kls[nt * 16 + lm][kb * 32 + lg * 8];
                acc = MFMA16(kh_f, qh[kb], acc);
                acc = MFMA16(kl_f, qh[kb], acc);
                acc = MFMA16(kh_f, ql[kb], acc);
            }
            sacc[nt] = acc;
        }
        // sacc[nt][r] = S[key = nt*16 + lg*4 + r][query = lm]

        // ---- per-lane online softmax (query lm), T13 defer-max ----
        float pmax = fmaxf(fmaxf(fmaxf(sacc[0][0], sacc[0][1]),
                                 fmaxf(sacc[0][2], sacc[0][3])),
                           fmaxf(fmaxf(sacc[1][0], sacc[1][1]),
                                 fmaxf(sacc[1][2], sacc[1][3])));
        pmax = fmaxf(pmax, __shfl_xor(pmax, 16));
        pmax = fmaxf(pmax, __shfl_xor(pmax, 32));
        if (__any(pmax - mrun > 8.f)) {          // rare after first tile
            const float mnew = fmaxf(mrun, pmax);
            const float corr = __expf(mrun - mnew);
            mrun = mnew;
            lsm *= corr;
            float c4[4];
#pragma unroll
            for (int r = 0; r < 4; ++r) c4[r] = __shfl(corr, lg * 4 + r);
#pragma unroll
            for (int nt = 0; nt < 8; ++nt) {
#pragma unroll
                for (int r = 0; r < 4; ++r) o[nt][r] *= c4[r];
            }
        }
        float p[8];
#pragma unroll
        for (int r = 0; r < 4; ++r) {
            p[r]     = __expf(sacc[0][r] - mrun);   // keys lg*4+r
            p[4 + r] = __expf(sacc[1][r] - mrun);   // keys 16+lg*4+r
        }
        float ls = ((p[0] + p[1]) + (p[2] + p[3])) +
                   ((p[4] + p[5]) + (p[6] + p[7]));
        ls += __shfl_xor(ls, 16);
        ls += __shfl_xor(ls, 32);
        lsm += ls;

        // ---- pack hi/lo bf16 pairs and bounce through wave-local LDS ----
        u32x4 hw, lw;
#pragma unroll
        for (int i = 0; i < 4; ++i) {
            const u16 h0 = f2bf_t(p[2 * i]);
            const u16 h1 = f2bf_t(p[2 * i + 1]);
            hw[i] = (unsigned)h0 | ((unsigned)h1 << 16);
            const u16 e0 = f2bf_t(p[2 * i] - bf2f(h0));
            const u16 e1 = f2bf_t(p[2 * i + 1] - bf2f(h1));
            lw[i] = (unsigned)e0 | ((unsigned)e1 << 16);
        }
        *(u32x4*)&Pw[t][0] = hw;
        *(u32x4*)&Pw[t][4] = lw;
        // wave-local: rows w*64..w*64+63 written/read only by wave w
        const u32x2 hA = *(const u32x2*)&Pw[prowA][pcol];
        const u32x2 hB = *(const u32x2*)&Pw[prowB][pcol];
        const u32x2 lA = *(const u32x2*)&Pw[prowA][pcol + 4];
        const u32x2 lB = *(const u32x2*)&Pw[prowB][pcol + 4];
        const u32x4 phw = {hA[0], hA[1], hB[0], hB[1]};
        const u32x4 plw = {lA[0], lA[1], lB[0], lB[1]};
        const s16x8 pHf = __builtin_bit_cast(s16x8, phw);
        const s16x8 pLf = __builtin_bit_cast(s16x8, plw);

        // ---- PV phase: O[q][d] += P * V ----
#pragma unroll
        for (int nt = 0; nt < 8; ++nt) {
            const s16x8 vf = *(const s16x8*)&Vs[nt * 16 + lm][lg * 8];
            o[nt] = MFMA16(pHf, vf, o[nt]);
            o[nt] = MFMA16(pLf, vf, o[nt]);
        }

        // rotate prefetch registers
        pk0 = nk0; pk1 = nk1; pl0 = nl0; pl1 = nl1; pv0 = nv0; pv1 = nv1;
    }

    // ---- epilogue: divide by l, write O as bf16 hi/lo [b][s][h*128+d] ----
    const int bb = bh >> 4;
    const int hh = bh & 15;
    const float invl = 1.f / lsm;        // for query lm
    float inv[4];
#pragma unroll
    for (int r = 0; r < 4; ++r) inv[r] = __shfl(invl, lg * 4 + r);
#pragma unroll
    for (int nt = 0; nt < 8; ++nt) {
#pragma unroll
        for (int r = 0; r < 4; ++r) {
            const int qrow = q0 + woff + lg * 4 + r;
            const size_t idx =
                ((size_t)bb * SEQ + qrow) * DMODEL + hh * DK + nt * 16 + lm;
            const float y = o[nt][r] * inv[r];
            const u16 hb = f2bf_t(y);
            Ohi[idx] = hb;
            Olo[idx] = f2bf_t(y - bf2f(hb));
        }
    }
}

extern "C" void kernel_launch(void* const* d_in, const int* in_sizes, int n_in,
                              void* d_out, int out_size, void* d_ws, size_t ws_size,
                              hipStream_t stream) {
    const float* x  = (const float*)d_in[0];
    const float* wq = (const float*)d_in[1];
    const float* wk = (const float*)d_in[2];
    const float* wv = (const float*)d_in[3];
    const float* wo = (const float*)d_in[4];

    const size_t NE = (size_t)MROWS * DMODEL;    // 16,777,216
    const size_t WE = (size_t)DMODEL * DMODEL;   // 4,194,304

    // ws layout (u16 elems), total 7*NE u16 = 234.88 MB:
    //   [0,NE)        Qhi   (after attn: reused for Woh/Wol)
    //   [NE,2NE)      Qlo
    //   [2NE,3NE)     Khi
    //   [3NE,4NE)     Klo
    //   [4NE,5NE)     Vt
    //   [5NE,6.5NE)   Wqkv hi (3*WE) + lo (3*WE)  -- dead after qkv_proj
    //   [5NE,7NE)     Ohi, Olo                     -- written by attn
    // X split lives in d_out (dead until out_proj overwrites it).
    u16* Qhi = (u16*)d_ws;
    u16* Qlo = Qhi + NE;
    u16* Khi = Qhi + 2 * NE;
    u16* Klo = Qhi + 3 * NE;
    u16* Vt  = Qhi + 4 * NE;
    u16* Wqkvh = Qhi + 5 * NE;
    u16* Wqkvl = Wqkvh + 3 * WE;
    u16* Ohi = Qhi + 5 * NE;       // aliases Wqkv region (lifetimes disjoint)
    u16* Olo = Ohi + NE;
    u16* Woh = Qhi;                // aliases dead Qhi region (split after attn)
    u16* Wol = Woh + WE;
    u16* Xhi = (u16*)d_out;        // d_out scratch until out_proj
    u16* Xlo = Xhi + NE;

    dim3 blk(256);
    split_bf16_kernel<<<dim3(1024), blk, 0, stream>>>(x, Xhi, Xlo, (int)(NE / 8));
    split_bf16_kernel<<<dim3(512), blk, 0, stream>>>(wq, Wqkvh, Wqkvl, (int)(WE / 8));
    split_bf16_kernel<<<dim3(512), blk, 0, stream>>>(wk, Wqkvh + WE, Wqkvl + WE, (int)(WE / 8));
    split_bf16_kernel<<<dim3(512), blk, 0, stream>>>(wv, Wqkvh + 2 * WE, Wqkvl + 2 * WE, (int)(WE / 8));

    qkv_proj_mfma<<<dim3(48, 64), blk, 0, stream>>>(Xhi, Xlo, Wqkvh, Wqkvl,
                                                    Qhi, Qlo, Khi, Klo, Vt);
    attn_kernel<<<dim3(SEQ / 64, BATCH * NHEADS), blk, 0, stream>>>(
        Qhi, Qlo, Khi, Klo, Vt, Ohi, Olo);

    split_bf16_kernel<<<dim3(512), blk, 0, stream>>>(wo, Woh, Wol, (int)(WE / 8));
    out_proj_mfma<<<dim3(16, 64), blk, 0, stream>>>(Ohi, Olo, Woh, Wol, (float*)d_out);
}